// Round 12
// baseline (122.382 us; speedup 1.0000x reference)
//
#include <hip/hip_runtime.h>
#include <math.h>

// B=8, G=2048, K=32, N=64.
// Algebraic simplification (verified): e_x is constant along the K axis that
// up/down average over => k_anp_x = mean(ff,K) exactly; std_dev/p/nrm/lc/e_x
// branch is dead code. kl = 2*mean(ff,K); the norm over G cancels the 2.
// Everything feeding fourier_B is linear in 1/std => projection on RAW diffs,
// inv applied once at the end (sort order invariant under inv>0).
//
//  k1/k1f : global std(diff, ddof=1) (two-stage double reduce)
//  k2     : row-in-REGISTERS (no LDS tile, no global_load_lds, no asm waits):
//           4x dwordx4 per quarter, register double-buffer (static names),
//           one vmcnt family so the compiler emits fine-grained counted
//           waits; 68 @ fB(68x32) via v_pk_fma_f32; butterfly K-reduce.
//  k3p/k3r: inv_r[b,c] = 1/||M[b,:,c]||_G  (coalesced 2-stage)
//  k3b    : out[b,c,g] = gelu(M*inv_r) - lc_line ; out[b,64+c,g] = lc_line

constexpr int Gg = 2048;

typedef float v2f __attribute__((ext_vector_type(2)));

constexpr size_t PART_OFF = 0;       // k1: 2048*2 doubles; k3p: 128*64 f32
constexpr size_t STD_OFF  = 32768;   // 1 float
constexpr size_t INVR_OFF = 33024;   // 512 floats
constexpr size_t M_OFF    = 65536;   // 8*2048*64 floats = 4 MiB

// ---------------- K1: partial sums for global std ----------------
__global__ __launch_bounds__(256) void k1_partial(const float4* __restrict__ knn4,
                                                  const float4* __restrict__ lc4,
                                                  double* __restrict__ part)
{
    int tid  = threadIdx.x;
    int base = blockIdx.x * 256 + tid;
    float4 q[16];
    #pragma unroll
    for (int i = 0; i < 16; ++i) q[i] = knn4[base + i * 524288];
    double s = 0.0, s2 = 0.0;
    #pragma unroll
    for (int i = 0; i < 16; ++i) {
        int idx = base + i * 524288;
        float4 l = lc4[(idx >> 9) * 16 + (idx & 15)];
        float d0 = q[i].x - l.x, d1 = q[i].y - l.y, d2 = q[i].z - l.z, d3 = q[i].w - l.w;
        s += (double)d0; s += (double)d1; s += (double)d2; s += (double)d3;
        s2 = fma((double)d0, (double)d0, s2);
        s2 = fma((double)d1, (double)d1, s2);
        s2 = fma((double)d2, (double)d2, s2);
        s2 = fma((double)d3, (double)d3, s2);
    }
    __shared__ double sh[512];
    sh[tid] = s; sh[256 + tid] = s2;
    __syncthreads();
    for (int off = 128; off > 0; off >>= 1) {
        if (tid < off) { sh[tid] += sh[tid + off]; sh[256 + tid] += sh[256 + tid + off]; }
        __syncthreads();
    }
    if (tid == 0) { part[blockIdx.x * 2] = sh[0]; part[blockIdx.x * 2 + 1] = sh[256]; }
}

__global__ __launch_bounds__(256) void k1_final(const double* __restrict__ part,
                                                float* __restrict__ stdp)
{
    int tid = threadIdx.x;
    double s = 0.0, s2 = 0.0;
    for (int i = tid; i < 2048; i += 256) { s += part[2*i]; s2 += part[2*i+1]; }
    __shared__ double sh[512];
    sh[tid] = s; sh[256 + tid] = s2;
    __syncthreads();
    for (int off = 128; off > 0; off >>= 1) {
        if (tid < off) { sh[tid] += sh[tid + off]; sh[256 + tid] += sh[256 + tid + off]; }
        __syncthreads();
    }
    if (tid == 0) {
        double S = sh[0], S2 = sh[256];
        double Mn = 33554432.0;
        double var = (S2 - S * S / Mn) / (Mn - 1.0);
        stdp[0] = (float)sqrt(var);
    }
}

// ---------------- K2: main fused kernel ----------------
// Thread owns one row, streamed through REGISTERS in quarters (64 B each):
// qa0..qa3 / qb0..qb3 double-buffer (static names -> stays in VGPRs).
// Per-instruction stride is 256 B, but each 64-B line is consumed by 4
// back-to-back dwordx4 of the same lane -> L1 MSHR-coalesced, no overfetch.
// knn + fB loads share one vmcnt family; compiler inserts counted waits.
__global__ __launch_bounds__(256, 4) void k2_main(const float* __restrict__ knn,
                                                  const float* __restrict__ lc,
                                                  const float* __restrict__ fB,
                                                  const float* __restrict__ stdp,
                                                  float* __restrict__ M)
{
    __shared__ float4 lcs[8][16];      // 2 KB, wave-private halves

    const int tid = threadIdx.x;
    const int w   = tid >> 6;
    const int l   = tid & 63;
    const int grp = tid >> 5;

    const float4* rowp = (const float4*)knn + ((size_t)blockIdx.x * 256 + tid) * 16;

    float4 lreg = make_float4(0.f, 0.f, 0.f, 0.f);
    if (l < 32)
        lreg = ((const float4*)lc)[(size_t)(blockIdx.x * 8 + 2 * w + (l >> 4)) * 16 + (l & 15)];

    // quarters 0 and 1 into registers
    float4 qa0 = rowp[0],  qa1 = rowp[1],  qa2 = rowp[2],  qa3 = rowp[3];
    float4 qb0 = rowp[4],  qb1 = rowp[5],  qb2 = rowp[6],  qb3 = rowp[7];

    if (l < 32) lcs[2 * w + (l >> 4)][l & 15] = lreg;   // wave-private

    const float inv = 1.0f / (stdp[0] + 1e-5f);

    v2f acc2[16];
    #pragma unroll
    for (int c = 0; c < 16; ++c) acc2[c] = (v2f){0.0f, 0.0f};
    float dot = 0.0f;
    float kn0 = 0, kn1 = 0, kn2 = 0, ln0 = 0, ln1 = 0, ln2 = 0;

#define CHUNK(q, jj, qv)                                                      \
    {                                                                         \
        float4 lv = lcs[grp][(q) * 4 + (jj)];                                 \
        float e0 = (qv).x - lv.x, e1 = (qv).y - lv.y,                         \
              e2 = (qv).z - lv.z, e3 = (qv).w - lv.w;                         \
        if ((q) == 0 && (jj) == 0) {                                          \
            kn0 = e0; kn1 = e1; kn2 = e2;                                     \
            ln0 = lv.x; ln1 = lv.y; ln2 = lv.z;                               \
        }                                                                     \
        dot = fmaf(e0, lv.x, dot); dot = fmaf(e1, lv.y, dot);                 \
        dot = fmaf(e2, lv.z, dot); dot = fmaf(e3, lv.w, dot);                 \
        const v2f* fr2 = (const v2f*)(fB + ((q) * 4 + (jj)) * 128);           \
        v2f ev0 = (v2f){e0, e0}, ev1 = (v2f){e1, e1};                         \
        v2f ev2 = (v2f){e2, e2}, ev3 = (v2f){e3, e3};                         \
        _Pragma("unroll")                                                     \
        for (int c = 0; c < 16; ++c)                                          \
            acc2[c] = __builtin_elementwise_fma(ev0, fr2[c],      acc2[c]);   \
        _Pragma("unroll")                                                     \
        for (int c = 0; c < 16; ++c)                                          \
            acc2[c] = __builtin_elementwise_fma(ev1, fr2[16 + c], acc2[c]);   \
        _Pragma("unroll")                                                     \
        for (int c = 0; c < 16; ++c)                                          \
            acc2[c] = __builtin_elementwise_fma(ev2, fr2[32 + c], acc2[c]);   \
        _Pragma("unroll")                                                     \
        for (int c = 0; c < 16; ++c)                                          \
            acc2[c] = __builtin_elementwise_fma(ev3, fr2[48 + c], acc2[c]);   \
    }

    // quarter 0 (regs qa*), then refill qa* with quarter 2
    CHUNK(0, 0, qa0) CHUNK(0, 1, qa1) CHUNK(0, 2, qa2) CHUNK(0, 3, qa3)
    qa0 = rowp[8];  qa1 = rowp[9];  qa2 = rowp[10]; qa3 = rowp[11];
    // quarter 1 (regs qb*), then refill qb* with quarter 3
    CHUNK(1, 0, qb0) CHUNK(1, 1, qb1) CHUNK(1, 2, qb2) CHUNK(1, 3, qb3)
    qb0 = rowp[12]; qb1 = rowp[13]; qb2 = rowp[14]; qb3 = rowp[15];
    // quarter 2
    CHUNK(2, 0, qa0) CHUNK(2, 1, qa1) CHUNK(2, 2, qa2) CHUNK(2, 3, qa3)
    // quarter 3
    CHUNK(3, 0, qb0) CHUNK(3, 1, qb1) CHUNK(3, 2, qb2) CHUNK(3, 3, qb3)

#undef CHUNK

    // descending sort3 of raw d[0:3] and lc[0:3] (inv>0 preserves order)
    float a0 = kn0, a1 = kn1, a2 = kn2;
    float b0 = ln0, b1 = ln1, b2 = ln2;
    float t;
    if (a0 < a1) { t = a0; a0 = a1; a1 = t; }
    if (a1 < a2) { t = a1; a1 = a2; a2 = t; }
    if (a0 < a1) { t = a0; a0 = a1; a1 = t; }
    if (b0 < b1) { t = b0; b0 = b1; b1 = t; }
    if (b1 < b2) { t = b1; b1 = b2; b2 = t; }
    if (b0 < b1) { t = b0; b0 = b1; b1 = t; }

    float cr0 = a1 * b2 - a2 * b1;     // raw cross; inv scales through
    float cr1 = a2 * b0 - a0 * b2;
    float cr2 = a0 * b1 - a1 * b0;
    {
        const v2f* fr2 = (const v2f*)(fB + 64 * 32);
        v2f ev0 = (v2f){cr0, cr0}, ev1 = (v2f){cr1, cr1};
        v2f ev2 = (v2f){cr2, cr2}, ev3 = (v2f){dot, dot};
        #pragma unroll
        for (int c = 0; c < 16; ++c)
            acc2[c] = __builtin_elementwise_fma(ev0, fr2[c],      acc2[c]);
        #pragma unroll
        for (int c = 0; c < 16; ++c)
            acc2[c] = __builtin_elementwise_fma(ev1, fr2[16 + c], acc2[c]);
        #pragma unroll
        for (int c = 0; c < 16; ++c)
            acc2[c] = __builtin_elementwise_fma(ev2, fr2[32 + c], acc2[c]);
        #pragma unroll
        for (int c = 0; c < 16; ++c)
            acc2[c] = __builtin_elementwise_fma(ev3, fr2[48 + c], acc2[c]);
    }

    // phase = inv*acc revolutions; exact reduction r = a - rint(a); hw sin/cos
    const float* acc = (const float*)acc2;      // acc[i] = column i
    float vs[32], vc[32];
    #pragma unroll
    for (int c = 0; c < 32; ++c) {
        float a = acc[c] * inv;
        float r = a - rintf(a);
        vs[c] = __builtin_amdgcn_sinf(r);
        vc[c] = __builtin_amdgcn_cosf(r);
    }

    // butterfly-compaction reduce over the 32 K-lanes; lane ends holding the
    // full K-sum for column c = lane&31.
    float s1[16], c1[16];
    #pragma unroll
    for (int j = 0; j < 16; ++j) {
        float ea = vs[2*j]   + __shfl_xor(vs[2*j],   1);
        float eb = vs[2*j+1] + __shfl_xor(vs[2*j+1], 1);
        s1[j] = (tid & 1) ? eb : ea;
        float fa = vc[2*j]   + __shfl_xor(vc[2*j],   1);
        float fb = vc[2*j+1] + __shfl_xor(vc[2*j+1], 1);
        c1[j] = (tid & 1) ? fb : fa;
    }
    float s2[8], c2[8];
    #pragma unroll
    for (int j = 0; j < 8; ++j) {
        float ea = s1[2*j]   + __shfl_xor(s1[2*j],   2);
        float eb = s1[2*j+1] + __shfl_xor(s1[2*j+1], 2);
        s2[j] = (tid & 2) ? eb : ea;
        float fa = c1[2*j]   + __shfl_xor(c1[2*j],   2);
        float fb = c1[2*j+1] + __shfl_xor(c1[2*j+1], 2);
        c2[j] = (tid & 2) ? fb : fa;
    }
    float s3[4], c3[4];
    #pragma unroll
    for (int j = 0; j < 4; ++j) {
        float ea = s2[2*j]   + __shfl_xor(s2[2*j],   4);
        float eb = s2[2*j+1] + __shfl_xor(s2[2*j+1], 4);
        s3[j] = (tid & 4) ? eb : ea;
        float fa = c2[2*j]   + __shfl_xor(c2[2*j],   4);
        float fb = c2[2*j+1] + __shfl_xor(c2[2*j+1], 4);
        c3[j] = (tid & 4) ? fb : fa;
    }
    float s4[2], c4[2];
    #pragma unroll
    for (int j = 0; j < 2; ++j) {
        float ea = s3[2*j]   + __shfl_xor(s3[2*j],   8);
        float eb = s3[2*j+1] + __shfl_xor(s3[2*j+1], 8);
        s4[j] = (tid & 8) ? eb : ea;
        float fa = c3[2*j]   + __shfl_xor(c3[2*j],   8);
        float fb = c3[2*j+1] + __shfl_xor(c3[2*j+1], 8);
        c4[j] = (tid & 8) ? fb : fa;
    }
    float ea = s4[0] + __shfl_xor(s4[0], 16);
    float eb = s4[1] + __shfl_xor(s4[1], 16);
    float ssum = ((tid & 16) ? eb : ea) * (1.0f / 32.0f);
    float fa = c4[0] + __shfl_xor(c4[0], 16);
    float fb = c4[1] + __shfl_xor(c4[1], 16);
    float csum = ((tid & 16) ? fb : fa) * (1.0f / 32.0f);

    const int cc   = tid & 31;
    const int mrow = blockIdx.x * 8 + grp;      // = b*G+g
    M[(size_t)mrow * 64 + cc]      = ssum;
    M[(size_t)mrow * 64 + 32 + cc] = csum;
}

// ---------------- K3p: per-(b,gb) partial ssq over 128 g, coalesced ----------------
__global__ __launch_bounds__(256) void k3_part(const float* __restrict__ M,
                                               float* __restrict__ part2)
{
    int blk = blockIdx.x;                 // b*16 + gb
    int b = blk >> 4, gb = blk & 15;
    int t = threadIdx.x;
    int c = t & 63, gs = t >> 6;          // 0..3
    const float* base = M + ((size_t)(b * Gg + gb * 128 + gs)) * 64 + c;
    float ss = 0.0f;
    #pragma unroll
    for (int i = 0; i < 32; ++i) {        // g = gb*128 + gs + 4*i
        float v = base[(size_t)i * 256];
        ss = fmaf(v, v, ss);
    }
    __shared__ float sh[256];
    sh[t] = ss;
    __syncthreads();
    if (t < 64) part2[blk * 64 + t] = sh[t] + sh[t + 64] + sh[t + 128] + sh[t + 192];
}

__global__ __launch_bounds__(64) void k3_rfin(const float* __restrict__ part2,
                                              float* __restrict__ invr)
{
    int b = blockIdx.x, c = threadIdx.x;
    float s = 0.0f;
    #pragma unroll
    for (int gb = 0; gb < 16; ++gb) s += part2[(b * 16 + gb) * 64 + c];
    invr[b * 64 + c] = 1.0f / sqrtf(s);
}

// ---------------- K3b: finalize ----------------
__global__ __launch_bounds__(256) void k3_final(const float* __restrict__ M,
                                                const float* __restrict__ lc,
                                                const float* __restrict__ invr,
                                                float* __restrict__ out)
{
    __shared__ float mt[64][65];
    __shared__ float lt[64][65];
    __shared__ float ir[64];
    __shared__ float iln[64];
    int tid = threadIdx.x;
    int b  = blockIdx.x >> 5;
    int g0 = (blockIdx.x & 31) * 64;
    if (tid < 64) ir[tid] = invr[b * 64 + tid];
    const float* Mb = M  + ((size_t)(b * Gg + g0)) * 64;
    const float* Lb = lc + ((size_t)(b * Gg + g0)) * 64;
    #pragma unroll
    for (int i = 0; i < 4; ++i) {
        int f = i * 1024 + tid * 4;
        int r = f >> 6, col = f & 63;
        float4 mv = *(const float4*)(Mb + f);
        float4 lv = *(const float4*)(Lb + f);
        mt[r][col] = mv.x; mt[r][col+1] = mv.y; mt[r][col+2] = mv.z; mt[r][col+3] = mv.w;
        lt[r][col] = lv.x; lt[r][col+1] = lv.y; lt[r][col+2] = lv.z; lt[r][col+3] = lv.w;
    }
    __syncthreads();
    if (tid < 64) {
        float ss = 0.0f;
        #pragma unroll
        for (int c = 0; c < 64; ++c) { float v = lt[tid][c]; ss = fmaf(v, v, ss); }
        iln[tid] = 1.0f / sqrtf(ss);
    }
    __syncthreads();
    int gl = tid & 63;
    int c0 = tid >> 6;                    // 0..3, wave-uniform
    float il = iln[gl];
    int obase = (b * 128) * Gg + g0 + gl;
    #pragma unroll
    for (int i = 0; i < 16; ++i) {
        int c = c0 + i * 4;
        float lcl = lt[gl][c] * il;
        float x = mt[gl][c] * ir[c];
        float kl = 0.5f * x * (1.0f + erff(x * 0.70710678118654752f));
        out[obase + c * Gg]        = kl - lcl;   // line_element
        out[obase + (c + 64) * Gg] = lcl;        // lc_line
    }
}

extern "C" void kernel_launch(void* const* d_in, const int* in_sizes, int n_in,
                              void* d_out, int out_size, void* d_ws, size_t ws_size,
                              hipStream_t stream)
{
    (void)in_sizes; (void)n_in; (void)out_size; (void)ws_size;
    const float* lc  = (const float*)d_in[0];   // (8,2048,64)
    const float* knn = (const float*)d_in[1];   // (8,2048,32,64)
    const float* fB  = (const float*)d_in[2];   // (68,32)
    float* out = (float*)d_out;                 // (8,128,2048) f32
    char* ws = (char*)d_ws;
    double* part  = (double*)(ws + PART_OFF);
    float*  part2 = (float*)(ws + PART_OFF);
    float*  stdp  = (float*)(ws + STD_OFF);
    float*  invr  = (float*)(ws + INVR_OFF);
    float*  M     = (float*)(ws + M_OFF);

    hipLaunchKernelGGL(k1_partial, dim3(2048), dim3(256), 0, stream,
                       (const float4*)knn, (const float4*)lc, part);
    hipLaunchKernelGGL(k1_final, dim3(1), dim3(256), 0, stream, part, stdp);
    hipLaunchKernelGGL(k2_main, dim3(2048), dim3(256), 0, stream,
                       knn, lc, fB, stdp, M);
    hipLaunchKernelGGL(k3_part, dim3(128), dim3(256), 0, stream, M, part2);
    hipLaunchKernelGGL(k3_rfin, dim3(8), dim3(64), 0, stream, part2, invr);
    hipLaunchKernelGGL(k3_final, dim3(256), dim3(256), 0, stream, M, lc, invr, out);
}

// Round 13
// 108.991 us; speedup vs baseline: 1.1229x; 1.1229x over previous
//
#include <hip/hip_runtime.h>
#include <math.h>

// B=8, G=2048, K=32, N=64.
// Algebraic simplification (verified): e_x is constant along the K axis that
// up/down average over => k_anp_x = mean(ff,K) exactly; std_dev/p/nrm/lc/e_x
// branch is dead code. kl = 2*mean(ff,K); the norm over G cancels the 2.
// Everything feeding fourier_B is linear in 1/std => projection on RAW diffs,
// inv applied once at the end (sort order invariant under inv>0).
//
//  k1/k1f : global std(diff, ddof=1) (two-stage double reduce)
//  k2     : COLUMN-RESIDENT fB. Phase 1: thread computes its row's 68
//           features -> elds[256][72] (LDS). Phase 2: lane owns col c=l&31
//           with fB[:,c] in 68 VGPRs; per row, broadcast ds_read_b128 of the
//           feature quad + 4 VGPR-only fmac; phase -> sincos -> running
//           K-sum in-thread (no butterfly, no SMEM stream, no asm).
//  k3p/k3r: inv_r[b,c] = 1/||M[b,:,c]||_G  (coalesced 2-stage)
//  k3b    : out[b,c,g] = gelu(M*inv_r) - lc_line ; out[b,64+c,g] = lc_line

constexpr int Gg = 2048;

constexpr size_t PART_OFF = 0;       // k1: 2048*2 doubles; k3p: 128*64 f32
constexpr size_t STD_OFF  = 32768;   // 1 float
constexpr size_t INVR_OFF = 33024;   // 512 floats
constexpr size_t M_OFF    = 65536;   // 8*2048*64 floats = 4 MiB

// ---------------- K1: partial sums for global std ----------------
__global__ __launch_bounds__(256) void k1_partial(const float4* __restrict__ knn4,
                                                  const float4* __restrict__ lc4,
                                                  double* __restrict__ part)
{
    int tid  = threadIdx.x;
    int base = blockIdx.x * 256 + tid;
    float4 q[16];
    #pragma unroll
    for (int i = 0; i < 16; ++i) q[i] = knn4[base + i * 524288];
    double s = 0.0, s2 = 0.0;
    #pragma unroll
    for (int i = 0; i < 16; ++i) {
        int idx = base + i * 524288;
        float4 l = lc4[(idx >> 9) * 16 + (idx & 15)];
        float d0 = q[i].x - l.x, d1 = q[i].y - l.y, d2 = q[i].z - l.z, d3 = q[i].w - l.w;
        s += (double)d0; s += (double)d1; s += (double)d2; s += (double)d3;
        s2 = fma((double)d0, (double)d0, s2);
        s2 = fma((double)d1, (double)d1, s2);
        s2 = fma((double)d2, (double)d2, s2);
        s2 = fma((double)d3, (double)d3, s2);
    }
    __shared__ double sh[512];
    sh[tid] = s; sh[256 + tid] = s2;
    __syncthreads();
    for (int off = 128; off > 0; off >>= 1) {
        if (tid < off) { sh[tid] += sh[tid + off]; sh[256 + tid] += sh[256 + tid + off]; }
        __syncthreads();
    }
    if (tid == 0) { part[blockIdx.x * 2] = sh[0]; part[blockIdx.x * 2 + 1] = sh[256]; }
}

__global__ __launch_bounds__(256) void k1_final(const double* __restrict__ part,
                                                float* __restrict__ stdp)
{
    int tid = threadIdx.x;
    double s = 0.0, s2 = 0.0;
    for (int i = tid; i < 2048; i += 256) { s += part[2*i]; s2 += part[2*i+1]; }
    __shared__ double sh[512];
    sh[tid] = s; sh[256 + tid] = s2;
    __syncthreads();
    for (int off = 128; off > 0; off >>= 1) {
        if (tid < off) { sh[tid] += sh[tid + off]; sh[256 + tid] += sh[256 + tid + off]; }
        __syncthreads();
    }
    if (tid == 0) {
        double S = sh[0], S2 = sh[256];
        double Mn = 33554432.0;
        double var = (S2 - S * S / Mn) / (Mn - 1.0);
        stdp[0] = (float)sqrt(var);
    }
}

// ---------------- K2: main fused kernel ----------------
// Block = 256 rows = 8 g. Phase 1: thread t computes features of row t
// (e[0..63] = raw diffs, e[64..67] = cross0..2, dot) into elds[t][..].
// Phase 2: half-wave h of wave w serves g_local = 2w+h; lane's col c = l&31;
// fB[:,c] lives in 68 VGPRs (fully unrolled load => static indices).
// Per row r: 17 broadcast b128 reads (uniform addr per half-wave) + 68 fmac
// into 4 partial chains; phase*inv -> exact revolution reduction -> hw
// sin/cos -> running sums. M[g][c] = ssum/32, M[g][32+c] = csum/32.
__global__ __launch_bounds__(256, 2) void k2_main(const float* __restrict__ knn,
                                                  const float* __restrict__ lc,
                                                  const float* __restrict__ fB,
                                                  const float* __restrict__ stdp,
                                                  float* __restrict__ M)
{
    __shared__ float elds[256][72];    // 73.7 KB; stride 288 B (16B-aligned)

    const int tid = threadIdx.x;
    const int l   = tid & 63;
    const int gl  = tid >> 5;          // g_local 0..7 (phase-1 row's g; also
                                       // phase-2 half-wave's g: (tid>>6)*2+((l>>5)&1) == tid>>5)
    const float4* rowp = (const float4*)knn + ((size_t)blockIdx.x * 256 + tid) * 16;
    const float4* lcp  = (const float4*)lc  + ((size_t)blockIdx.x * 8 + gl) * 16;

    // ---- phase 1: features for own row ----
    float dot = 0.0f;
    float kn0 = 0, kn1 = 0, kn2 = 0, ln0 = 0, ln1 = 0, ln2 = 0;
    #pragma unroll
    for (int q = 0; q < 16; ++q) {
        float4 qv = rowp[q];
        float4 lv = lcp[q];
        float e0 = qv.x - lv.x, e1 = qv.y - lv.y;
        float e2 = qv.z - lv.z, e3 = qv.w - lv.w;
        if (q == 0) {
            kn0 = e0; kn1 = e1; kn2 = e2;
            ln0 = lv.x; ln1 = lv.y; ln2 = lv.z;
        }
        dot = fmaf(e0, lv.x, dot); dot = fmaf(e1, lv.y, dot);
        dot = fmaf(e2, lv.z, dot); dot = fmaf(e3, lv.w, dot);
        *(float4*)&elds[tid][q * 4] = make_float4(e0, e1, e2, e3);
    }
    {   // descending sort3 of raw d[0:3] and lc[0:3] (inv>0 preserves order)
        float a0 = kn0, a1 = kn1, a2 = kn2;
        float b0 = ln0, b1 = ln1, b2 = ln2;
        float t;
        if (a0 < a1) { t = a0; a0 = a1; a1 = t; }
        if (a1 < a2) { t = a1; a1 = a2; a2 = t; }
        if (a0 < a1) { t = a0; a0 = a1; a1 = t; }
        if (b0 < b1) { t = b0; b0 = b1; b1 = t; }
        if (b1 < b2) { t = b1; b1 = b2; b2 = t; }
        if (b0 < b1) { t = b0; b0 = b1; b1 = t; }
        float cr0 = a1 * b2 - a2 * b1;   // raw cross; inv scales through
        float cr1 = a2 * b0 - a0 * b2;
        float cr2 = a0 * b1 - a1 * b0;
        *(float4*)&elds[tid][64] = make_float4(cr0, cr1, cr2, dot);
    }

    // ---- fB column into registers (static indices via full unroll) ----
    const int c = l & 31;
    float fbr[68];
    #pragma unroll
    for (int k = 0; k < 68; ++k) fbr[k] = fB[k * 32 + c];

    __syncthreads();

    const float inv = 1.0f / (stdp[0] + 1e-5f);
    const int rbase = tid & ~31;        // rows of this half-wave's g

    float ssum = 0.0f, csum = 0.0f;
    #pragma unroll 2
    for (int r = 0; r < 32; ++r) {
        const float* e = elds[rbase + r];   // uniform per half-wave: broadcast
        float a0 = 0.f, a1 = 0.f, a2 = 0.f, a3 = 0.f;
        #pragma unroll
        for (int kq = 0; kq < 17; ++kq) {
            float4 e4 = *(const float4*)&e[kq * 4];
            a0 = fmaf(e4.x, fbr[4 * kq],     a0);
            a1 = fmaf(e4.y, fbr[4 * kq + 1], a1);
            a2 = fmaf(e4.z, fbr[4 * kq + 2], a2);
            a3 = fmaf(e4.w, fbr[4 * kq + 3], a3);
        }
        float a  = ((a0 + a1) + (a2 + a3)) * inv;     // revolutions
        float rr = a - rintf(a);                       // exact reduction
        ssum += __builtin_amdgcn_sinf(rr);
        csum += __builtin_amdgcn_cosf(rr);
    }

    const int g = blockIdx.x * 8 + gl;
    M[(size_t)g * 64 + c]      = ssum * (1.0f / 32.0f);
    M[(size_t)g * 64 + 32 + c] = csum * (1.0f / 32.0f);
}

// ---------------- K3p: per-(b,gb) partial ssq over 128 g, coalesced ----------------
__global__ __launch_bounds__(256) void k3_part(const float* __restrict__ M,
                                               float* __restrict__ part2)
{
    int blk = blockIdx.x;                 // b*16 + gb
    int b = blk >> 4, gb = blk & 15;
    int t = threadIdx.x;
    int c = t & 63, gs = t >> 6;          // 0..3
    const float* base = M + ((size_t)(b * Gg + gb * 128 + gs)) * 64 + c;
    float ss = 0.0f;
    #pragma unroll
    for (int i = 0; i < 32; ++i) {        // g = gb*128 + gs + 4*i
        float v = base[(size_t)i * 256];
        ss = fmaf(v, v, ss);
    }
    __shared__ float sh[256];
    sh[t] = ss;
    __syncthreads();
    if (t < 64) part2[blk * 64 + t] = sh[t] + sh[t + 64] + sh[t + 128] + sh[t + 192];
}

__global__ __launch_bounds__(64) void k3_rfin(const float* __restrict__ part2,
                                              float* __restrict__ invr)
{
    int b = blockIdx.x, c = threadIdx.x;
    float s = 0.0f;
    #pragma unroll
    for (int gb = 0; gb < 16; ++gb) s += part2[(b * 16 + gb) * 64 + c];
    invr[b * 64 + c] = 1.0f / sqrtf(s);
}

// ---------------- K3b: finalize ----------------
__global__ __launch_bounds__(256) void k3_final(const float* __restrict__ M,
                                                const float* __restrict__ lc,
                                                const float* __restrict__ invr,
                                                float* __restrict__ out)
{
    __shared__ float mt[64][65];
    __shared__ float lt[64][65];
    __shared__ float ir[64];
    __shared__ float iln[64];
    int tid = threadIdx.x;
    int b  = blockIdx.x >> 5;
    int g0 = (blockIdx.x & 31) * 64;
    if (tid < 64) ir[tid] = invr[b * 64 + tid];
    const float* Mb = M  + ((size_t)(b * Gg + g0)) * 64;
    const float* Lb = lc + ((size_t)(b * Gg + g0)) * 64;
    #pragma unroll
    for (int i = 0; i < 4; ++i) {
        int f = i * 1024 + tid * 4;
        int r = f >> 6, col = f & 63;
        float4 mv = *(const float4*)(Mb + f);
        float4 lv = *(const float4*)(Lb + f);
        mt[r][col] = mv.x; mt[r][col+1] = mv.y; mt[r][col+2] = mv.z; mt[r][col+3] = mv.w;
        lt[r][col] = lv.x; lt[r][col+1] = lv.y; lt[r][col+2] = lv.z; lt[r][col+3] = lv.w;
    }
    __syncthreads();
    if (tid < 64) {
        float ss = 0.0f;
        #pragma unroll
        for (int c = 0; c < 64; ++c) { float v = lt[tid][c]; ss = fmaf(v, v, ss); }
        iln[tid] = 1.0f / sqrtf(ss);
    }
    __syncthreads();
    int gl = tid & 63;
    int c0 = tid >> 6;                    // 0..3, wave-uniform
    float il = iln[gl];
    int obase = (b * 128) * Gg + g0 + gl;
    #pragma unroll
    for (int i = 0; i < 16; ++i) {
        int c = c0 + i * 4;
        float lcl = lt[gl][c] * il;
        float x = mt[gl][c] * ir[c];
        float kl = 0.5f * x * (1.0f + erff(x * 0.70710678118654752f));
        out[obase + c * Gg]        = kl - lcl;   // line_element
        out[obase + (c + 64) * Gg] = lcl;        // lc_line
    }
}

extern "C" void kernel_launch(void* const* d_in, const int* in_sizes, int n_in,
                              void* d_out, int out_size, void* d_ws, size_t ws_size,
                              hipStream_t stream)
{
    (void)in_sizes; (void)n_in; (void)out_size; (void)ws_size;
    const float* lc  = (const float*)d_in[0];   // (8,2048,64)
    const float* knn = (const float*)d_in[1];   // (8,2048,32,64)
    const float* fB  = (const float*)d_in[2];   // (68,32)
    float* out = (float*)d_out;                 // (8,128,2048) f32
    char* ws = (char*)d_ws;
    double* part  = (double*)(ws + PART_OFF);
    float*  part2 = (float*)(ws + PART_OFF);
    float*  stdp  = (float*)(ws + STD_OFF);
    float*  invr  = (float*)(ws + INVR_OFF);
    float*  M     = (float*)(ws + M_OFF);

    hipLaunchKernelGGL(k1_partial, dim3(2048), dim3(256), 0, stream,
                       (const float4*)knn, (const float4*)lc, part);
    hipLaunchKernelGGL(k1_final, dim3(1), dim3(256), 0, stream, part, stdp);
    hipLaunchKernelGGL(k2_main, dim3(2048), dim3(256), 0, stream,
                       knn, lc, fB, stdp, M);
    hipLaunchKernelGGL(k3_part, dim3(128), dim3(256), 0, stream, M, part2);
    hipLaunchKernelGGL(k3_rfin, dim3(8), dim3(64), 0, stream, part2, invr);
    hipLaunchKernelGGL(k3_final, dim3(256), dim3(256), 0, stream, M, lc, invr, out);
}

// Round 14
// 95.013 us; speedup vs baseline: 1.2880x; 1.1471x over previous
//
#include <hip/hip_runtime.h>
#include <math.h>

// B=8, G=2048, K=32, N=64.
// Algebraic simplification (verified): e_x is constant along the K axis that
// up/down average over => k_anp_x = mean(ff,K) exactly; std_dev/p/nrm/lc/e_x
// branch is dead code. kl = 2*mean(ff,K); the norm over G cancels the 2.
// Everything feeding fourier_B is linear in 1/std => projection on RAW diffs,
// inv applied once at the end (sort order invariant under inv>0).
//
//  k1/k1f : global std(diff, ddof=1) (two-stage double reduce)
//  k2     : COLUMN-RESIDENT fB (R13) + transposed feature store
//           elds4[quad][row] (conflict-free writes, broadcast reads) +
//           v_pk_fma_f32 inner product (34 pk/row).
//  k3p/k3r: inv_r[b,c] = 1/||M[b,:,c]||_G  (coalesced 2-stage)
//  k3b    : out[b,c,g] = gelu(M*inv_r) - lc_line ; out[b,64+c,g] = lc_line

constexpr int Gg = 2048;

typedef float v2f __attribute__((ext_vector_type(2)));

constexpr size_t PART_OFF = 0;       // k1: 2048*2 doubles; k3p: 128*64 f32
constexpr size_t STD_OFF  = 32768;   // 1 float
constexpr size_t INVR_OFF = 33024;   // 512 floats
constexpr size_t M_OFF    = 65536;   // 8*2048*64 floats = 4 MiB

// ---------------- K1: partial sums for global std ----------------
__global__ __launch_bounds__(256) void k1_partial(const float4* __restrict__ knn4,
                                                  const float4* __restrict__ lc4,
                                                  double* __restrict__ part)
{
    int tid  = threadIdx.x;
    int base = blockIdx.x * 256 + tid;
    float4 q[16];
    #pragma unroll
    for (int i = 0; i < 16; ++i) q[i] = knn4[base + i * 524288];
    double s = 0.0, s2 = 0.0;
    #pragma unroll
    for (int i = 0; i < 16; ++i) {
        int idx = base + i * 524288;
        float4 l = lc4[(idx >> 9) * 16 + (idx & 15)];
        float d0 = q[i].x - l.x, d1 = q[i].y - l.y, d2 = q[i].z - l.z, d3 = q[i].w - l.w;
        s += (double)d0; s += (double)d1; s += (double)d2; s += (double)d3;
        s2 = fma((double)d0, (double)d0, s2);
        s2 = fma((double)d1, (double)d1, s2);
        s2 = fma((double)d2, (double)d2, s2);
        s2 = fma((double)d3, (double)d3, s2);
    }
    __shared__ double sh[512];
    sh[tid] = s; sh[256 + tid] = s2;
    __syncthreads();
    for (int off = 128; off > 0; off >>= 1) {
        if (tid < off) { sh[tid] += sh[tid + off]; sh[256 + tid] += sh[256 + tid + off]; }
        __syncthreads();
    }
    if (tid == 0) { part[blockIdx.x * 2] = sh[0]; part[blockIdx.x * 2 + 1] = sh[256]; }
}

__global__ __launch_bounds__(256) void k1_final(const double* __restrict__ part,
                                                float* __restrict__ stdp)
{
    int tid = threadIdx.x;
    double s = 0.0, s2 = 0.0;
    for (int i = tid; i < 2048; i += 256) { s += part[2*i]; s2 += part[2*i+1]; }
    __shared__ double sh[512];
    sh[tid] = s; sh[256 + tid] = s2;
    __syncthreads();
    for (int off = 128; off > 0; off >>= 1) {
        if (tid < off) { sh[tid] += sh[tid + off]; sh[256 + tid] += sh[256 + tid + off]; }
        __syncthreads();
    }
    if (tid == 0) {
        double S = sh[0], S2 = sh[256];
        double Mn = 33554432.0;
        double var = (S2 - S * S / Mn) / (Mn - 1.0);
        stdp[0] = (float)sqrt(var);
    }
}

// ---------------- K2: main fused kernel ----------------
// Block = 256 rows = 8 g. Phase 1: thread t computes features of row t
// (quads 0..15 = raw diffs, quad 16 = cross0..2,dot) into elds4[quad][t]
// (TRANSPOSED: writes are lane-consecutive 16B slots -> conflict-free;
// reads are uniform per half-wave -> broadcast, conflict-free).
// Phase 2: half-wave serves g_local = tid>>5; lane's col c = l&31; fB[:,c]
// lives in 34 v2f registers. Per row: 17 broadcast b128 + 34 v_pk_fma_f32
// (parity-split accA/accB reproduces the scalar ((a0+a1)+(a2+a3)) order
// bit-exactly); phase*inv -> exact revolution reduction -> hw sin/cos ->
// running K-sums. M[g][c] = ssum/32, M[g][32+c] = csum/32.
__global__ __launch_bounds__(256, 2) void k2_main(const float* __restrict__ knn,
                                                  const float* __restrict__ lc,
                                                  const float* __restrict__ fB,
                                                  const float* __restrict__ stdp,
                                                  float* __restrict__ M)
{
    __shared__ float4 elds4[17][256];  // 69.6 KB, transposed

    const int tid = threadIdx.x;
    const int l   = tid & 63;
    const int gl  = tid >> 5;          // g_local 0..7

    const float4* rowp = (const float4*)knn + ((size_t)blockIdx.x * 256 + tid) * 16;
    const float4* lcp  = (const float4*)lc  + ((size_t)blockIdx.x * 8 + gl) * 16;

    // ---- phase 1: features for own row ----
    float dot = 0.0f;
    float kn0 = 0, kn1 = 0, kn2 = 0, ln0 = 0, ln1 = 0, ln2 = 0;
    #pragma unroll
    for (int q = 0; q < 16; ++q) {
        float4 qv = rowp[q];
        float4 lv = lcp[q];
        float e0 = qv.x - lv.x, e1 = qv.y - lv.y;
        float e2 = qv.z - lv.z, e3 = qv.w - lv.w;
        if (q == 0) {
            kn0 = e0; kn1 = e1; kn2 = e2;
            ln0 = lv.x; ln1 = lv.y; ln2 = lv.z;
        }
        dot = fmaf(e0, lv.x, dot); dot = fmaf(e1, lv.y, dot);
        dot = fmaf(e2, lv.z, dot); dot = fmaf(e3, lv.w, dot);
        elds4[q][tid] = make_float4(e0, e1, e2, e3);
    }
    {   // descending sort3 of raw d[0:3] and lc[0:3] (inv>0 preserves order)
        float a0 = kn0, a1 = kn1, a2 = kn2;
        float b0 = ln0, b1 = ln1, b2 = ln2;
        float t;
        if (a0 < a1) { t = a0; a0 = a1; a1 = t; }
        if (a1 < a2) { t = a1; a1 = a2; a2 = t; }
        if (a0 < a1) { t = a0; a0 = a1; a1 = t; }
        if (b0 < b1) { t = b0; b0 = b1; b1 = t; }
        if (b1 < b2) { t = b1; b1 = b2; b2 = t; }
        if (b0 < b1) { t = b0; b0 = b1; b1 = t; }
        float cr0 = a1 * b2 - a2 * b1;   // raw cross; inv scales through
        float cr1 = a2 * b0 - a0 * b2;
        float cr2 = a0 * b1 - a1 * b0;
        elds4[16][tid] = make_float4(cr0, cr1, cr2, dot);
    }

    // ---- fB column into registers as v2f pairs (static indices) ----
    const int c = l & 31;
    v2f fbr2[34];
    #pragma unroll
    for (int j = 0; j < 34; ++j)
        fbr2[j] = (v2f){fB[(2 * j) * 32 + c], fB[(2 * j + 1) * 32 + c]};

    __syncthreads();

    const float inv = 1.0f / (stdp[0] + 1e-5f);
    const int rbase = tid & ~31;        // rows of this half-wave's g

    float ssum = 0.0f, csum = 0.0f;
    #pragma unroll 2
    for (int r = 0; r < 32; ++r) {
        const int row = rbase + r;      // uniform per half-wave: broadcast
        v2f accA = (v2f){0.f, 0.f};     // sums k ≡ 0,1 (mod 4)
        v2f accB = (v2f){0.f, 0.f};     // sums k ≡ 2,3 (mod 4)
        #pragma unroll
        for (int kq = 0; kq < 17; ++kq) {
            float4 e4 = elds4[kq][row];
            accA = __builtin_elementwise_fma((v2f){e4.x, e4.y}, fbr2[2 * kq],     accA);
            accB = __builtin_elementwise_fma((v2f){e4.z, e4.w}, fbr2[2 * kq + 1], accB);
        }
        float a  = ((accA.x + accA.y) + (accB.x + accB.y)) * inv;  // revolutions
        float rr = a - rintf(a);                                    // exact
        ssum += __builtin_amdgcn_sinf(rr);
        csum += __builtin_amdgcn_cosf(rr);
    }

    const int g = blockIdx.x * 8 + gl;
    M[(size_t)g * 64 + c]      = ssum * (1.0f / 32.0f);
    M[(size_t)g * 64 + 32 + c] = csum * (1.0f / 32.0f);
}

// ---------------- K3p: per-(b,gb) partial ssq over 128 g, coalesced ----------------
__global__ __launch_bounds__(256) void k3_part(const float* __restrict__ M,
                                               float* __restrict__ part2)
{
    int blk = blockIdx.x;                 // b*16 + gb
    int b = blk >> 4, gb = blk & 15;
    int t = threadIdx.x;
    int c = t & 63, gs = t >> 6;          // 0..3
    const float* base = M + ((size_t)(b * Gg + gb * 128 + gs)) * 64 + c;
    float ss = 0.0f;
    #pragma unroll
    for (int i = 0; i < 32; ++i) {        // g = gb*128 + gs + 4*i
        float v = base[(size_t)i * 256];
        ss = fmaf(v, v, ss);
    }
    __shared__ float sh[256];
    sh[t] = ss;
    __syncthreads();
    if (t < 64) part2[blk * 64 + t] = sh[t] + sh[t + 64] + sh[t + 128] + sh[t + 192];
}

__global__ __launch_bounds__(64) void k3_rfin(const float* __restrict__ part2,
                                              float* __restrict__ invr)
{
    int b = blockIdx.x, c = threadIdx.x;
    float s = 0.0f;
    #pragma unroll
    for (int gb = 0; gb < 16; ++gb) s += part2[(b * 16 + gb) * 64 + c];
    invr[b * 64 + c] = 1.0f / sqrtf(s);
}

// ---------------- K3b: finalize ----------------
__global__ __launch_bounds__(256) void k3_final(const float* __restrict__ M,
                                                const float* __restrict__ lc,
                                                const float* __restrict__ invr,
                                                float* __restrict__ out)
{
    __shared__ float mt[64][65];
    __shared__ float lt[64][65];
    __shared__ float ir[64];
    __shared__ float iln[64];
    int tid = threadIdx.x;
    int b  = blockIdx.x >> 5;
    int g0 = (blockIdx.x & 31) * 64;
    if (tid < 64) ir[tid] = invr[b * 64 + tid];
    const float* Mb = M  + ((size_t)(b * Gg + g0)) * 64;
    const float* Lb = lc + ((size_t)(b * Gg + g0)) * 64;
    #pragma unroll
    for (int i = 0; i < 4; ++i) {
        int f = i * 1024 + tid * 4;
        int r = f >> 6, col = f & 63;
        float4 mv = *(const float4*)(Mb + f);
        float4 lv = *(const float4*)(Lb + f);
        mt[r][col] = mv.x; mt[r][col+1] = mv.y; mt[r][col+2] = mv.z; mt[r][col+3] = mv.w;
        lt[r][col] = lv.x; lt[r][col+1] = lv.y; lt[r][col+2] = lv.z; lt[r][col+3] = lv.w;
    }
    __syncthreads();
    if (tid < 64) {
        float ss = 0.0f;
        #pragma unroll
        for (int c = 0; c < 64; ++c) { float v = lt[tid][c]; ss = fmaf(v, v, ss); }
        iln[tid] = 1.0f / sqrtf(ss);
    }
    __syncthreads();
    int gl = tid & 63;
    int c0 = tid >> 6;                    // 0..3, wave-uniform
    float il = iln[gl];
    int obase = (b * 128) * Gg + g0 + gl;
    #pragma unroll
    for (int i = 0; i < 16; ++i) {
        int c = c0 + i * 4;
        float lcl = lt[gl][c] * il;
        float x = mt[gl][c] * ir[c];
        float kl = 0.5f * x * (1.0f + erff(x * 0.70710678118654752f));
        out[obase + c * Gg]        = kl - lcl;   // line_element
        out[obase + (c + 64) * Gg] = lcl;        // lc_line
    }
}

extern "C" void kernel_launch(void* const* d_in, const int* in_sizes, int n_in,
                              void* d_out, int out_size, void* d_ws, size_t ws_size,
                              hipStream_t stream)
{
    (void)in_sizes; (void)n_in; (void)out_size; (void)ws_size;
    const float* lc  = (const float*)d_in[0];   // (8,2048,64)
    const float* knn = (const float*)d_in[1];   // (8,2048,32,64)
    const float* fB  = (const float*)d_in[2];   // (68,32)
    float* out = (float*)d_out;                 // (8,128,2048) f32
    char* ws = (char*)d_ws;
    double* part  = (double*)(ws + PART_OFF);
    float*  part2 = (float*)(ws + PART_OFF);
    float*  stdp  = (float*)(ws + STD_OFF);
    float*  invr  = (float*)(ws + INVR_OFF);
    float*  M     = (float*)(ws + M_OFF);

    hipLaunchKernelGGL(k1_partial, dim3(2048), dim3(256), 0, stream,
                       (const float4*)knn, (const float4*)lc, part);
    hipLaunchKernelGGL(k1_final, dim3(1), dim3(256), 0, stream, part, stdp);
    hipLaunchKernelGGL(k2_main, dim3(2048), dim3(256), 0, stream,
                       knn, lc, fB, stdp, M);
    hipLaunchKernelGGL(k3_part, dim3(128), dim3(256), 0, stream, M, part2);
    hipLaunchKernelGGL(k3_rfin, dim3(8), dim3(64), 0, stream, part2, invr);
    hipLaunchKernelGGL(k3_final, dim3(256), dim3(256), 0, stream, M, lc, invr, out);
}

// Round 15
// 93.922 us; speedup vs baseline: 1.3030x; 1.0116x over previous
//
#include <hip/hip_runtime.h>
#include <math.h>

// B=8, G=2048, K=32, N=64.
// Algebraic simplification (verified): e_x is constant along the K axis that
// up/down average over => k_anp_x = mean(ff,K) exactly; std_dev/p/nrm/lc/e_x
// branch is dead code. kl = 2*mean(ff,K); the norm over G cancels the 2.
// Everything feeding fourier_B is linear in 1/std => projection on RAW diffs,
// inv applied once at the end (sort order invariant under inv>0).
//
//  k1/k1f : global std(diff, ddof=1); per-thread f32 4-chain partials,
//           f64 only across threads (k1 is BW-bound, not f64-VALU-bound)
//  k2     : COLUMN-RESIDENT fB + transposed feature store elds4[quad][row]
//           + v_pk_fma_f32; TWO ROWS PER ITERATION (4 independent fma
//           chains -> latency hidden at 2 waves/SIMD).
//  k3p/k3r: inv_r[b,c] = 1/||M[b,:,c]||_G  (coalesced 2-stage)
//  k3b    : out[b,c,g] = gelu(M*inv_r) - lc_line ; out[b,64+c,g] = lc_line

constexpr int Gg = 2048;

typedef float v2f __attribute__((ext_vector_type(2)));

constexpr size_t PART_OFF = 0;       // k1: 2048*2 doubles; k3p: 128*64 f32
constexpr size_t STD_OFF  = 32768;   // 1 float
constexpr size_t INVR_OFF = 33024;   // 512 floats
constexpr size_t M_OFF    = 65536;   // 8*2048*64 floats = 4 MiB

// ---------------- K1: partial sums for global std ----------------
__global__ __launch_bounds__(256) void k1_partial(const float4* __restrict__ knn4,
                                                  const float4* __restrict__ lc4,
                                                  double* __restrict__ part)
{
    int tid  = threadIdx.x;
    int base = blockIdx.x * 256 + tid;
    float4 q[16];
    #pragma unroll
    for (int i = 0; i < 16; ++i) q[i] = knn4[base + i * 524288];
    // f32 4-chain partials over this thread's 64 values (rel err ~1e-7),
    // promoted to f64 once per thread.
    float s0 = 0.f, s1 = 0.f, s2c = 0.f, s3 = 0.f;
    float q0 = 0.f, q1 = 0.f, q2c = 0.f, q3 = 0.f;
    #pragma unroll
    for (int i = 0; i < 16; ++i) {
        int idx = base + i * 524288;
        float4 l = lc4[(idx >> 9) * 16 + (idx & 15)];
        float d0 = q[i].x - l.x, d1 = q[i].y - l.y, d2 = q[i].z - l.z, d3 = q[i].w - l.w;
        s0 += d0; s1 += d1; s2c += d2; s3 += d3;
        q0 = fmaf(d0, d0, q0);
        q1 = fmaf(d1, d1, q1);
        q2c = fmaf(d2, d2, q2c);
        q3 = fmaf(d3, d3, q3);
    }
    double s  = (double)s0 + (double)s1 + (double)s2c + (double)s3;
    double s2 = (double)q0 + (double)q1 + (double)q2c + (double)q3;
    __shared__ double sh[512];
    sh[tid] = s; sh[256 + tid] = s2;
    __syncthreads();
    for (int off = 128; off > 0; off >>= 1) {
        if (tid < off) { sh[tid] += sh[tid + off]; sh[256 + tid] += sh[256 + tid + off]; }
        __syncthreads();
    }
    if (tid == 0) { part[blockIdx.x * 2] = sh[0]; part[blockIdx.x * 2 + 1] = sh[256]; }
}

__global__ __launch_bounds__(256) void k1_final(const double* __restrict__ part,
                                                float* __restrict__ stdp)
{
    int tid = threadIdx.x;
    double s = 0.0, s2 = 0.0;
    for (int i = tid; i < 2048; i += 256) { s += part[2*i]; s2 += part[2*i+1]; }
    __shared__ double sh[512];
    sh[tid] = s; sh[256 + tid] = s2;
    __syncthreads();
    for (int off = 128; off > 0; off >>= 1) {
        if (tid < off) { sh[tid] += sh[tid + off]; sh[256 + tid] += sh[256 + tid + off]; }
        __syncthreads();
    }
    if (tid == 0) {
        double S = sh[0], S2 = sh[256];
        double Mn = 33554432.0;
        double var = (S2 - S * S / Mn) / (Mn - 1.0);
        stdp[0] = (float)sqrt(var);
    }
}

// ---------------- K2: main fused kernel ----------------
// Block = 256 rows = 8 g. Phase 1: thread t computes features of row t
// (quads 0..15 = raw diffs, quad 16 = cross0..2,dot) into elds4[quad][t]
// (transposed: conflict-free writes, broadcast reads).
// Phase 2: half-wave serves g_local = tid>>5; lane's col c = l&31; fB[:,c]
// in 34 v2f regs. TWO rows per iteration: 4 independent pk_fma chains
// (latency-hidden), 34 broadcast b128 reads pipelined by the compiler.
// Per-row dot order identical to R14 (parity chains); only the sin/cos
// accumulation order changes (row-parity split) - ulp-level.
__global__ __launch_bounds__(256, 2) void k2_main(const float* __restrict__ knn,
                                                  const float* __restrict__ lc,
                                                  const float* __restrict__ fB,
                                                  const float* __restrict__ stdp,
                                                  float* __restrict__ M)
{
    __shared__ float4 elds4[17][256];  // 69.6 KB, transposed

    const int tid = threadIdx.x;
    const int l   = tid & 63;
    const int gl  = tid >> 5;          // g_local 0..7

    const float4* rowp = (const float4*)knn + ((size_t)blockIdx.x * 256 + tid) * 16;
    const float4* lcp  = (const float4*)lc  + ((size_t)blockIdx.x * 8 + gl) * 16;

    // ---- phase 1: features for own row ----
    float dot = 0.0f;
    float kn0 = 0, kn1 = 0, kn2 = 0, ln0 = 0, ln1 = 0, ln2 = 0;
    #pragma unroll
    for (int q = 0; q < 16; ++q) {
        float4 qv = rowp[q];
        float4 lv = lcp[q];
        float e0 = qv.x - lv.x, e1 = qv.y - lv.y;
        float e2 = qv.z - lv.z, e3 = qv.w - lv.w;
        if (q == 0) {
            kn0 = e0; kn1 = e1; kn2 = e2;
            ln0 = lv.x; ln1 = lv.y; ln2 = lv.z;
        }
        dot = fmaf(e0, lv.x, dot); dot = fmaf(e1, lv.y, dot);
        dot = fmaf(e2, lv.z, dot); dot = fmaf(e3, lv.w, dot);
        elds4[q][tid] = make_float4(e0, e1, e2, e3);
    }
    {   // descending sort3 of raw d[0:3] and lc[0:3] (inv>0 preserves order)
        float a0 = kn0, a1 = kn1, a2 = kn2;
        float b0 = ln0, b1 = ln1, b2 = ln2;
        float t;
        if (a0 < a1) { t = a0; a0 = a1; a1 = t; }
        if (a1 < a2) { t = a1; a1 = a2; a2 = t; }
        if (a0 < a1) { t = a0; a0 = a1; a1 = t; }
        if (b0 < b1) { t = b0; b0 = b1; b1 = t; }
        if (b1 < b2) { t = b1; b1 = b2; b2 = t; }
        if (b0 < b1) { t = b0; b0 = b1; b1 = t; }
        float cr0 = a1 * b2 - a2 * b1;   // raw cross; inv scales through
        float cr1 = a2 * b0 - a0 * b2;
        float cr2 = a0 * b1 - a1 * b0;
        elds4[16][tid] = make_float4(cr0, cr1, cr2, dot);
    }

    // ---- fB column into registers as v2f pairs (static indices) ----
    const int c = l & 31;
    v2f fbr2[34];
    #pragma unroll
    for (int j = 0; j < 34; ++j)
        fbr2[j] = (v2f){fB[(2 * j) * 32 + c], fB[(2 * j + 1) * 32 + c]};

    __syncthreads();

    const float inv = 1.0f / (stdp[0] + 1e-5f);
    const int rbase = tid & ~31;        // rows of this half-wave's g

    float ssum0 = 0.0f, csum0 = 0.0f;   // even rows
    float ssum1 = 0.0f, csum1 = 0.0f;   // odd rows
    for (int r = 0; r < 32; r += 2) {
        const int rowA = rbase + r;     // uniform per half-wave: broadcast
        const int rowB = rbase + r + 1;
        v2f aA0 = (v2f){0.f, 0.f}, aA1 = (v2f){0.f, 0.f};
        v2f aB0 = (v2f){0.f, 0.f}, aB1 = (v2f){0.f, 0.f};
        #pragma unroll
        for (int kq = 0; kq < 17; ++kq) {
            float4 eA = elds4[kq][rowA];
            float4 eB = elds4[kq][rowB];
            aA0 = __builtin_elementwise_fma((v2f){eA.x, eA.y}, fbr2[2 * kq],     aA0);
            aA1 = __builtin_elementwise_fma((v2f){eA.z, eA.w}, fbr2[2 * kq + 1], aA1);
            aB0 = __builtin_elementwise_fma((v2f){eB.x, eB.y}, fbr2[2 * kq],     aB0);
            aB1 = __builtin_elementwise_fma((v2f){eB.z, eB.w}, fbr2[2 * kq + 1], aB1);
        }
        float pA = ((aA0.x + aA0.y) + (aA1.x + aA1.y)) * inv;  // revolutions
        float pB = ((aB0.x + aB0.y) + (aB1.x + aB1.y)) * inv;
        float rA = pA - rintf(pA);                              // exact
        float rB = pB - rintf(pB);
        ssum0 += __builtin_amdgcn_sinf(rA);
        csum0 += __builtin_amdgcn_cosf(rA);
        ssum1 += __builtin_amdgcn_sinf(rB);
        csum1 += __builtin_amdgcn_cosf(rB);
    }
    float ssum = ssum0 + ssum1;
    float csum = csum0 + csum1;

    const int g = blockIdx.x * 8 + gl;
    M[(size_t)g * 64 + c]      = ssum * (1.0f / 32.0f);
    M[(size_t)g * 64 + 32 + c] = csum * (1.0f / 32.0f);
}

// ---------------- K3p: per-(b,gb) partial ssq over 128 g, coalesced ----------------
__global__ __launch_bounds__(256) void k3_part(const float* __restrict__ M,
                                               float* __restrict__ part2)
{
    int blk = blockIdx.x;                 // b*16 + gb
    int b = blk >> 4, gb = blk & 15;
    int t = threadIdx.x;
    int c = t & 63, gs = t >> 6;          // 0..3
    const float* base = M + ((size_t)(b * Gg + gb * 128 + gs)) * 64 + c;
    float ss = 0.0f;
    #pragma unroll
    for (int i = 0; i < 32; ++i) {        // g = gb*128 + gs + 4*i
        float v = base[(size_t)i * 256];
        ss = fmaf(v, v, ss);
    }
    __shared__ float sh[256];
    sh[t] = ss;
    __syncthreads();
    if (t < 64) part2[blk * 64 + t] = sh[t] + sh[t + 64] + sh[t + 128] + sh[t + 192];
}

__global__ __launch_bounds__(64) void k3_rfin(const float* __restrict__ part2,
                                              float* __restrict__ invr)
{
    int b = blockIdx.x, c = threadIdx.x;
    float s = 0.0f;
    #pragma unroll
    for (int gb = 0; gb < 16; ++gb) s += part2[(b * 16 + gb) * 64 + c];
    invr[b * 64 + c] = 1.0f / sqrtf(s);
}

// ---------------- K3b: finalize ----------------
__global__ __launch_bounds__(256) void k3_final(const float* __restrict__ M,
                                                const float* __restrict__ lc,
                                                const float* __restrict__ invr,
                                                float* __restrict__ out)
{
    __shared__ float mt[64][65];
    __shared__ float lt[64][65];
    __shared__ float ir[64];
    __shared__ float iln[64];
    int tid = threadIdx.x;
    int b  = blockIdx.x >> 5;
    int g0 = (blockIdx.x & 31) * 64;
    if (tid < 64) ir[tid] = invr[b * 64 + tid];
    const float* Mb = M  + ((size_t)(b * Gg + g0)) * 64;
    const float* Lb = lc + ((size_t)(b * Gg + g0)) * 64;
    #pragma unroll
    for (int i = 0; i < 4; ++i) {
        int f = i * 1024 + tid * 4;
        int r = f >> 6, col = f & 63;
        float4 mv = *(const float4*)(Mb + f);
        float4 lv = *(const float4*)(Lb + f);
        mt[r][col] = mv.x; mt[r][col+1] = mv.y; mt[r][col+2] = mv.z; mt[r][col+3] = mv.w;
        lt[r][col] = lv.x; lt[r][col+1] = lv.y; lt[r][col+2] = lv.z; lt[r][col+3] = lv.w;
    }
    __syncthreads();
    if (tid < 64) {
        float ss = 0.0f;
        #pragma unroll
        for (int c = 0; c < 64; ++c) { float v = lt[tid][c]; ss = fmaf(v, v, ss); }
        iln[tid] = 1.0f / sqrtf(ss);
    }
    __syncthreads();
    int gl = tid & 63;
    int c0 = tid >> 6;                    // 0..3, wave-uniform
    float il = iln[gl];
    int obase = (b * 128) * Gg + g0 + gl;
    #pragma unroll
    for (int i = 0; i < 16; ++i) {
        int c = c0 + i * 4;
        float lcl = lt[gl][c] * il;
        float x = mt[gl][c] * ir[c];
        float kl = 0.5f * x * (1.0f + erff(x * 0.70710678118654752f));
        out[obase + c * Gg]        = kl - lcl;   // line_element
        out[obase + (c + 64) * Gg] = lcl;        // lc_line
    }
}

extern "C" void kernel_launch(void* const* d_in, const int* in_sizes, int n_in,
                              void* d_out, int out_size, void* d_ws, size_t ws_size,
                              hipStream_t stream)
{
    (void)in_sizes; (void)n_in; (void)out_size; (void)ws_size;
    const float* lc  = (const float*)d_in[0];   // (8,2048,64)
    const float* knn = (const float*)d_in[1];   // (8,2048,32,64)
    const float* fB  = (const float*)d_in[2];   // (68,32)
    float* out = (float*)d_out;                 // (8,128,2048) f32
    char* ws = (char*)d_ws;
    double* part  = (double*)(ws + PART_OFF);
    float*  part2 = (float*)(ws + PART_OFF);
    float*  stdp  = (float*)(ws + STD_OFF);
    float*  invr  = (float*)(ws + INVR_OFF);
    float*  M     = (float*)(ws + M_OFF);

    hipLaunchKernelGGL(k1_partial, dim3(2048), dim3(256), 0, stream,
                       (const float4*)knn, (const float4*)lc, part);
    hipLaunchKernelGGL(k1_final, dim3(1), dim3(256), 0, stream, part, stdp);
    hipLaunchKernelGGL(k2_main, dim3(2048), dim3(256), 0, stream,
                       knn, lc, fB, stdp, M);
    hipLaunchKernelGGL(k3_part, dim3(128), dim3(256), 0, stream, M, part2);
    hipLaunchKernelGGL(k3_rfin, dim3(8), dim3(64), 0, stream, part2, invr);
    hipLaunchKernelGGL(k3_final, dim3(256), dim3(256), 0, stream, M, lc, invr, out);
}

// Round 16
// 93.041 us; speedup vs baseline: 1.3154x; 1.0095x over previous
//
#include <hip/hip_runtime.h>
#include <math.h>

// B=8, G=2048, K=32, N=64.
// Algebraic simplification (verified): e_x is constant along the K axis that
// up/down average over => k_anp_x = mean(ff,K) exactly; std_dev/p/nrm/lc/e_x
// branch is dead code. kl = 2*mean(ff,K); the norm over G cancels the 2.
// Everything feeding fourier_B is linear in 1/std => projection on RAW diffs,
// inv applied once at the end (sort order invariant under inv>0).
//
//  k1/k1f : global std(diff, ddof=1); f32 4-chain per-thread partials
//  k2     : COLUMN-PAIR-RESIDENT fB (68 v2f/lane, 2 cols/lane) so one wave
//           serves 4 g's per broadcast ds_read -> LDS instructions halved
//           (the R15 bottleneck). Feature store swizzled slot = r*8+(g^(r&7))
//           so the 4 concurrent group addresses hit distinct bank-quads.
//           Two half-row partials per g combined via 4KB LDS + 1 barrier.
//  k3p/k3r: inv_r[b,c] = 1/||M[b,:,c]||_G  (coalesced 2-stage)
//  k3b    : out[b,c,g] = gelu(M*inv_r) - lc_line ; out[b,64+c,g] = lc_line

constexpr int Gg = 2048;

typedef float v2f __attribute__((ext_vector_type(2)));

constexpr size_t PART_OFF = 0;       // k1: 2048*2 doubles; k3p: 128*64 f32
constexpr size_t STD_OFF  = 32768;   // 1 float
constexpr size_t INVR_OFF = 33024;   // 512 floats
constexpr size_t M_OFF    = 65536;   // 8*2048*64 floats = 4 MiB

// ---------------- K1: partial sums for global std ----------------
__global__ __launch_bounds__(256) void k1_partial(const float4* __restrict__ knn4,
                                                  const float4* __restrict__ lc4,
                                                  double* __restrict__ part)
{
    int tid  = threadIdx.x;
    int base = blockIdx.x * 256 + tid;
    float4 q[16];
    #pragma unroll
    for (int i = 0; i < 16; ++i) q[i] = knn4[base + i * 524288];
    float s0 = 0.f, s1 = 0.f, s2c = 0.f, s3 = 0.f;
    float q0 = 0.f, q1 = 0.f, q2c = 0.f, q3 = 0.f;
    #pragma unroll
    for (int i = 0; i < 16; ++i) {
        int idx = base + i * 524288;
        float4 l = lc4[(idx >> 9) * 16 + (idx & 15)];
        float d0 = q[i].x - l.x, d1 = q[i].y - l.y, d2 = q[i].z - l.z, d3 = q[i].w - l.w;
        s0 += d0; s1 += d1; s2c += d2; s3 += d3;
        q0 = fmaf(d0, d0, q0);
        q1 = fmaf(d1, d1, q1);
        q2c = fmaf(d2, d2, q2c);
        q3 = fmaf(d3, d3, q3);
    }
    double s  = (double)s0 + (double)s1 + (double)s2c + (double)s3;
    double s2 = (double)q0 + (double)q1 + (double)q2c + (double)q3;
    __shared__ double sh[512];
    sh[tid] = s; sh[256 + tid] = s2;
    __syncthreads();
    for (int off = 128; off > 0; off >>= 1) {
        if (tid < off) { sh[tid] += sh[tid + off]; sh[256 + tid] += sh[256 + tid + off]; }
        __syncthreads();
    }
    if (tid == 0) { part[blockIdx.x * 2] = sh[0]; part[blockIdx.x * 2 + 1] = sh[256]; }
}

__global__ __launch_bounds__(256) void k1_final(const double* __restrict__ part,
                                                float* __restrict__ stdp)
{
    int tid = threadIdx.x;
    double s = 0.0, s2 = 0.0;
    for (int i = tid; i < 2048; i += 256) { s += part[2*i]; s2 += part[2*i+1]; }
    __shared__ double sh[512];
    sh[tid] = s; sh[256 + tid] = s2;
    __syncthreads();
    for (int off = 128; off > 0; off >>= 1) {
        if (tid < off) { sh[tid] += sh[tid + off]; sh[256 + tid] += sh[256 + tid + off]; }
        __syncthreads();
    }
    if (tid == 0) {
        double S = sh[0], S2 = sh[256];
        double Mn = 33554432.0;
        double var = (S2 - S * S / Mn) / (Mn - 1.0);
        stdp[0] = (float)sqrt(var);
    }
}

// ---------------- K2: main fused kernel ----------------
// Block = 256 rows = 8 g. Phase 1: thread tid (row g*32+r, g=tid>>5,
// r=tid&31) computes its 17 feature quads into elds4[quad][slot],
// slot = r*8 + (g ^ (r&7))  (write phases: 8 bank-quads x2 lanes = free;
// read phases: 4 consecutive-g groups -> 4 distinct bank-quads = free).
// Phase 2: wave w, group j = l>>4 serves g = (w&1)*4+j, rows
// half*16..half*16+15 (half = w>>1). Lane owns cols i2 = (l&15)*2, i2+1;
// fB pairs in 68 v2f regs. Per row: 17 broadcast b128 + 68 pk_fma in 2
// chains. Partials (16-row sums) combined across the two halves via LDS.
__global__ __launch_bounds__(256, 2) void k2_main(const float* __restrict__ knn,
                                                  const float* __restrict__ lc,
                                                  const float* __restrict__ fB,
                                                  const float* __restrict__ stdp,
                                                  float* __restrict__ M)
{
    __shared__ float4 elds4[17][256];  // 69.6 KB, swizzled slots
    __shared__ float  pls_s[2][256];   // 2 KB  (half, g*32+c)
    __shared__ float  pls_c[2][256];   // 2 KB

    const int tid = threadIdx.x;
    const int w   = tid >> 6;
    const int l   = tid & 63;
    const int gl  = tid >> 5;          // phase-1 row's g

    const float4* rowp = (const float4*)knn + ((size_t)blockIdx.x * 256 + tid) * 16;
    const float4* lcp  = (const float4*)lc  + ((size_t)blockIdx.x * 8 + gl) * 16;

    const int wslot = (tid & 31) * 8 + ((tid >> 5) ^ (tid & 7));

    // ---- phase 1: features for own row ----
    float dot = 0.0f;
    float kn0 = 0, kn1 = 0, kn2 = 0, ln0 = 0, ln1 = 0, ln2 = 0;
    #pragma unroll
    for (int q = 0; q < 16; ++q) {
        float4 qv = rowp[q];
        float4 lv = lcp[q];
        float e0 = qv.x - lv.x, e1 = qv.y - lv.y;
        float e2 = qv.z - lv.z, e3 = qv.w - lv.w;
        if (q == 0) {
            kn0 = e0; kn1 = e1; kn2 = e2;
            ln0 = lv.x; ln1 = lv.y; ln2 = lv.z;
        }
        dot = fmaf(e0, lv.x, dot); dot = fmaf(e1, lv.y, dot);
        dot = fmaf(e2, lv.z, dot); dot = fmaf(e3, lv.w, dot);
        elds4[q][wslot] = make_float4(e0, e1, e2, e3);
    }
    {   // descending sort3 of raw d[0:3] and lc[0:3] (inv>0 preserves order)
        float a0 = kn0, a1 = kn1, a2 = kn2;
        float b0 = ln0, b1 = ln1, b2 = ln2;
        float t;
        if (a0 < a1) { t = a0; a0 = a1; a1 = t; }
        if (a1 < a2) { t = a1; a1 = a2; a2 = t; }
        if (a0 < a1) { t = a0; a0 = a1; a1 = t; }
        if (b0 < b1) { t = b0; b0 = b1; b1 = t; }
        if (b1 < b2) { t = b1; b1 = b2; b2 = t; }
        if (b0 < b1) { t = b0; b0 = b1; b1 = t; }
        float cr0 = a1 * b2 - a2 * b1;   // raw cross; inv scales through
        float cr1 = a2 * b0 - a0 * b2;
        float cr2 = a0 * b1 - a1 * b0;
        elds4[16][wslot] = make_float4(cr0, cr1, cr2, dot);
    }

    // ---- fB column pair into registers (static indices) ----
    const int i2   = (l & 15) * 2;        // column pair base
    const int gj   = (w & 1) * 4 + (l >> 4);  // g served by this lane's group
    const int half = w >> 1;              // row half served
    v2f fbr2[68];
    #pragma unroll
    for (int k = 0; k < 68; ++k)
        fbr2[k] = *(const v2f*)&fB[k * 32 + i2];

    __syncthreads();

    const float inv = 1.0f / (stdp[0] + 1e-5f);

    v2f ssum = (v2f){0.f, 0.f}, csum = (v2f){0.f, 0.f};
    #pragma unroll 2
    for (int rr = 0; rr < 16; ++rr) {
        const int r    = half * 16 + rr;
        const int slot = r * 8 + (gj ^ (rr & 7));   // r&7 == rr&7
        v2f aP = (v2f){0.f, 0.f}, aQ = (v2f){0.f, 0.f};
        #pragma unroll
        for (int kq = 0; kq < 17; ++kq) {
            float4 e4 = elds4[kq][slot];
            aP = __builtin_elementwise_fma((v2f){e4.x, e4.x}, fbr2[4 * kq],     aP);
            aQ = __builtin_elementwise_fma((v2f){e4.y, e4.y}, fbr2[4 * kq + 1], aQ);
            aP = __builtin_elementwise_fma((v2f){e4.z, e4.z}, fbr2[4 * kq + 2], aP);
            aQ = __builtin_elementwise_fma((v2f){e4.w, e4.w}, fbr2[4 * kq + 3], aQ);
        }
        v2f p = (aP + aQ) * inv;                    // revolutions, per col
        float rx = p.x - rintf(p.x);                // exact reduction
        float ry = p.y - rintf(p.y);
        ssum.x += __builtin_amdgcn_sinf(rx);
        ssum.y += __builtin_amdgcn_sinf(ry);
        csum.x += __builtin_amdgcn_cosf(rx);
        csum.y += __builtin_amdgcn_cosf(ry);
    }

    // partial store (half, g, col-pair) and combine
    *(v2f*)&pls_s[half][gj * 32 + i2] = ssum;
    *(v2f*)&pls_c[half][gj * 32 + i2] = csum;
    __syncthreads();
    {
        const int g = tid >> 5, c = tid & 31;
        float sv = pls_s[0][tid] + pls_s[1][tid];
        float cv = pls_c[0][tid] + pls_c[1][tid];
        const size_t mrow = (size_t)(blockIdx.x * 8 + g) * 64;
        M[mrow + c]      = sv * (1.0f / 32.0f);
        M[mrow + 32 + c] = cv * (1.0f / 32.0f);
    }
}

// ---------------- K3p: per-(b,gb) partial ssq over 128 g, coalesced ----------------
__global__ __launch_bounds__(256) void k3_part(const float* __restrict__ M,
                                               float* __restrict__ part2)
{
    int blk = blockIdx.x;                 // b*16 + gb
    int b = blk >> 4, gb = blk & 15;
    int t = threadIdx.x;
    int c = t & 63, gs = t >> 6;          // 0..3
    const float* base = M + ((size_t)(b * Gg + gb * 128 + gs)) * 64 + c;
    float ss = 0.0f;
    #pragma unroll
    for (int i = 0; i < 32; ++i) {        // g = gb*128 + gs + 4*i
        float v = base[(size_t)i * 256];
        ss = fmaf(v, v, ss);
    }
    __shared__ float sh[256];
    sh[t] = ss;
    __syncthreads();
    if (t < 64) part2[blk * 64 + t] = sh[t] + sh[t + 64] + sh[t + 128] + sh[t + 192];
}

__global__ __launch_bounds__(64) void k3_rfin(const float* __restrict__ part2,
                                              float* __restrict__ invr)
{
    int b = blockIdx.x, c = threadIdx.x;
    float s = 0.0f;
    #pragma unroll
    for (int gb = 0; gb < 16; ++gb) s += part2[(b * 16 + gb) * 64 + c];
    invr[b * 64 + c] = 1.0f / sqrtf(s);
}

// ---------------- K3b: finalize ----------------
__global__ __launch_bounds__(256) void k3_final(const float* __restrict__ M,
                                                const float* __restrict__ lc,
                                                const float* __restrict__ invr,
                                                float* __restrict__ out)
{
    __shared__ float mt[64][65];
    __shared__ float lt[64][65];
    __shared__ float ir[64];
    __shared__ float iln[64];
    int tid = threadIdx.x;
    int b  = blockIdx.x >> 5;
    int g0 = (blockIdx.x & 31) * 64;
    if (tid < 64) ir[tid] = invr[b * 64 + tid];
    const float* Mb = M  + ((size_t)(b * Gg + g0)) * 64;
    const float* Lb = lc + ((size_t)(b * Gg + g0)) * 64;
    #pragma unroll
    for (int i = 0; i < 4; ++i) {
        int f = i * 1024 + tid * 4;
        int r = f >> 6, col = f & 63;
        float4 mv = *(const float4*)(Mb + f);
        float4 lv = *(const float4*)(Lb + f);
        mt[r][col] = mv.x; mt[r][col+1] = mv.y; mt[r][col+2] = mv.z; mt[r][col+3] = mv.w;
        lt[r][col] = lv.x; lt[r][col+1] = lv.y; lt[r][col+2] = lv.z; lt[r][col+3] = lv.w;
    }
    __syncthreads();
    if (tid < 64) {
        float ss = 0.0f;
        #pragma unroll
        for (int c = 0; c < 64; ++c) { float v = lt[tid][c]; ss = fmaf(v, v, ss); }
        iln[tid] = 1.0f / sqrtf(ss);
    }
    __syncthreads();
    int gl = tid & 63;
    int c0 = tid >> 6;                    // 0..3, wave-uniform
    float il = iln[gl];
    int obase = (b * 128) * Gg + g0 + gl;
    #pragma unroll
    for (int i = 0; i < 16; ++i) {
        int c = c0 + i * 4;
        float lcl = lt[gl][c] * il;
        float x = mt[gl][c] * ir[c];
        float kl = 0.5f * x * (1.0f + erff(x * 0.70710678118654752f));
        out[obase + c * Gg]        = kl - lcl;   // line_element
        out[obase + (c + 64) * Gg] = lcl;        // lc_line
    }
}

extern "C" void kernel_launch(void* const* d_in, const int* in_sizes, int n_in,
                              void* d_out, int out_size, void* d_ws, size_t ws_size,
                              hipStream_t stream)
{
    (void)in_sizes; (void)n_in; (void)out_size; (void)ws_size;
    const float* lc  = (const float*)d_in[0];   // (8,2048,64)
    const float* knn = (const float*)d_in[1];   // (8,2048,32,64)
    const float* fB  = (const float*)d_in[2];   // (68,32)
    float* out = (float*)d_out;                 // (8,128,2048) f32
    char* ws = (char*)d_ws;
    double* part  = (double*)(ws + PART_OFF);
    float*  part2 = (float*)(ws + PART_OFF);
    float*  stdp  = (float*)(ws + STD_OFF);
    float*  invr  = (float*)(ws + INVR_OFF);
    float*  M     = (float*)(ws + M_OFF);

    hipLaunchKernelGGL(k1_partial, dim3(2048), dim3(256), 0, stream,
                       (const float4*)knn, (const float4*)lc, part);
    hipLaunchKernelGGL(k1_final, dim3(1), dim3(256), 0, stream, part, stdp);
    hipLaunchKernelGGL(k2_main, dim3(2048), dim3(256), 0, stream,
                       knn, lc, fB, stdp, M);
    hipLaunchKernelGGL(k3_part, dim3(128), dim3(256), 0, stream, M, part2);
    hipLaunchKernelGGL(k3_rfin, dim3(8), dim3(64), 0, stream, part2, invr);
    hipLaunchKernelGGL(k3_final, dim3(256), dim3(256), 0, stream, M, lc, invr, out);
}